// Round 12
// baseline (1576.973 us; speedup 1.0000x reference)
//
#include <hip/hip_runtime.h>
#include <hip/hip_bf16.h>
#include <math.h>

#define N_NODES   100000
#define N_EDGES   3200000
#define IN_DIM    128
#define HID       64
#define OUT_DIM   10
#define N_GRAPHS  64

// Radix geometry: bucket = row >> 8 (256 rows/bucket), NBUCKET=391.
// Tile = 6250 edges, NTILES=512 = 2 blocks/CU. LDS-staged coalesced writes
// everywhere (round-1 lesson: random 8B global stores = 8x write amp).
// Round-11 lesson: f16 dot2/perm rewrite spilled gather results to scratch
// (WRITE 12.5->200MB, 26x slower) — inner loop stays in the round-9 bf16
// unpack-FMA form that is proven spill-free (VGPR 28).
#define BUCKET_SHIFT 8
#define BUCKET_ROWS  256
#define NBUCKET ((N_NODES + BUCKET_ROWS - 1) >> BUCKET_SHIFT)     // 391
#define TILE_EDGES 6250                                           // 512*6250 = 3.2M exact
#define NTILES (N_EDGES / TILE_EDGES)                             // 512
#define CPAD 16       // cursor padding: 16 ints = 64B line per bucket
#define CAP  9216     // bucket mean 8192, sigma ~90 -> 11-sigma margin
#define KMAX 18       // CAP / 512

typedef unsigned long long ull;
typedef unsigned short ushort;
typedef __attribute__((ext_vector_type(8))) short short8;   // 8 bf16 (4 VGPRs)
typedef __attribute__((ext_vector_type(4))) float f32x4;    // MFMA C/D

__device__ __forceinline__ ushort rne_bf16(float x) {
    unsigned u = __float_as_uint(x);
    return (ushort)((u + 0x7fffu + ((u >> 16) & 1u)) >> 16);
}
__device__ __forceinline__ float bf2f(ushort u) {
    return __uint_as_float((unsigned)u << 16);
}

// ---------------------------------------------------------------- hist
__global__ __launch_bounds__(1024) void hist391(const int* __restrict__ rows,
                                                int* __restrict__ histT,
                                                int* __restrict__ gcur) {
    __shared__ int h[NBUCKET];
    int t = threadIdx.x, tile = blockIdx.x;
    for (int i = t; i < NBUCKET; i += 1024) h[i] = 0;
    __syncthreads();
    int base = tile * TILE_EDGES;
#pragma unroll
    for (int k = 0; k < 7; k++) {
        int idx = k * 1024 + t;
        if (idx < TILE_EDGES) atomicAdd(&h[rows[base + idx] >> BUCKET_SHIFT], 1);
    }
    __syncthreads();
    for (int i = t; i < NBUCKET; i += 1024) {
        int v = h[i];
        histT[tile * NBUCKET + i] = v;
        if (v) atomicAdd(&gcur[i * CPAD], v);
    }
}

// ---------------------------------------------------------------- scan
// Exclusive-scan 391 bucket totals -> base[]; reset padded cursors; zero sums.
__global__ __launch_bounds__(512) void scan392(int* __restrict__ gcur,
                                               int* __restrict__ base,
                                               float* __restrict__ sums) {
    __shared__ int sc[512];
    int t = threadIdx.x;
    for (int i = t; i < N_GRAPHS * HID; i += 512) sums[i] = 0.f;
    int cntv = (t < NBUCKET) ? gcur[t * CPAD] : 0;
    sc[t] = cntv;
    __syncthreads();
    for (int off = 1; off < 512; off <<= 1) {
        int x = (t >= off) ? sc[t - off] : 0;
        __syncthreads();
        sc[t] += x;
        __syncthreads();
    }
    int excl = sc[t] - cntv;
    if (t < NBUCKET) { base[t] = excl; gcur[t * CPAD] = excl; }
    if (t == NBUCKET) base[NBUCKET] = excl;   // == N_EDGES
}

// ---------------------------------------------------------------- scatter
// Record: rowLocal(8b) | colbyte(24b, = col<<7) || val_f32(32b).
__global__ __launch_bounds__(1024) void scatter_pass(const int* __restrict__ rows,
                                                     const int* __restrict__ cols,
                                                     const float* __restrict__ vals,
                                                     const int* __restrict__ histT,
                                                     int* __restrict__ gcur,
                                                     ull* __restrict__ etmp) {
    __shared__ ull ebuf[TILE_EDGES];       // 50,000 B
    __shared__ ushort bkt[TILE_EDGES];     // 12,500 B
    __shared__ int sc[512];
    __shared__ int lcur[NBUCKET];
    __shared__ int gdelta[NBUCKET];        // total ~67.7 KB -> 2 blk/CU
    int t = threadIdx.x, tile = blockIdx.x;

    int cntv = 0;
    if (t < 512) {
        cntv = (t < NBUCKET) ? histT[tile * NBUCKET + t] : 0;
        sc[t] = cntv;
    }
    __syncthreads();
    for (int off = 1; off < 512; off <<= 1) {
        int x = 0;
        if (t < 512 && t >= off) x = sc[t - off];
        __syncthreads();
        if (t < 512) sc[t] += x;
        __syncthreads();
    }
    if (t < NBUCKET) {
        int excl = sc[t] - cntv;
        lcur[t] = excl;
        int gbase = cntv ? atomicAdd(&gcur[t * CPAD], cntv) : 0;
        gdelta[t] = gbase - excl;
    }
    __syncthreads();

    int base = tile * TILE_EDGES;
#pragma unroll
    for (int k = 0; k < 7; k++) {
        int idx = k * 1024 + t;
        if (idx < TILE_EDGES) {
            int e = base + idx;
            int r = rows[e];
            int b = r >> BUCKET_SHIFT;
            int pos = atomicAdd(&lcur[b], 1);     // LDS atomic, block-local
            unsigned hi = ((unsigned)(r & (BUCKET_ROWS - 1)) << 24)
                        | ((unsigned)cols[e] << 7);
            ebuf[pos] = ((ull)hi << 32) | (ull)__float_as_uint(vals[e]);
            bkt[pos] = (ushort)b;
        }
    }
    __syncthreads();
    for (int j = t; j < TILE_EDGES; j += 1024)
        etmp[gdelta[bkt[j]] + j] = ebuf[j];       // coalesced within runs
}

// ---------------------------------------------------------------- pass C
__global__ __launch_bounds__(512) void bucket_sort(const int* __restrict__ base,
                                                   const ull* __restrict__ etmp,
                                                   ull* __restrict__ edges,
                                                   int* __restrict__ row_ptr) {
    __shared__ int rcnt[BUCKET_ROWS];
    __shared__ int roff[BUCKET_ROWS];
    __shared__ int rcur[BUCKET_ROWS];
    __shared__ ull ebuf[CAP];              // 73,728 B -> 2 blk/CU
    int b = blockIdx.x, t = threadIdx.x;
    int s = base[b];
    int e = base[b + 1];
    int len = e - s;
    bool staged = (len <= CAP);

    ull rp[KMAX];
    if (t < BUCKET_ROWS) rcnt[t] = 0;
    __syncthreads();
    if (staged) {
#pragma unroll
        for (int k = 0; k < KMAX; k++) {
            int j = s + t + k * 512;
            if (j < e) { rp[k] = etmp[j]; atomicAdd(&rcnt[(int)(rp[k] >> 56)], 1); }
        }
    } else {
        for (int j = s + t; j < e; j += 512)
            atomicAdd(&rcnt[(int)(etmp[j] >> 56)], 1);
    }
    __syncthreads();
    if (t < BUCKET_ROWS) roff[t] = rcnt[t];
    __syncthreads();
    for (int off = 1; off < BUCKET_ROWS; off <<= 1) {
        int x = (t >= off && t < BUCKET_ROWS) ? roff[t - off] : 0;
        __syncthreads();
        if (t < BUCKET_ROWS) roff[t] += x;
        __syncthreads();
    }
    if (t < BUCKET_ROWS) {
        int excl = roff[t] - rcnt[t];
        rcur[t] = staged ? excl : s + excl;
        int grow = b * BUCKET_ROWS + t;
        if (grow < N_NODES) row_ptr[grow] = s + excl;
    }
    if (b == NBUCKET - 1 && t == 0) row_ptr[N_NODES] = N_EDGES;
    __syncthreads();

    if (staged) {
#pragma unroll
        for (int k = 0; k < KMAX; k++) {
            int j = s + t + k * 512;
            if (j < e) {
                ull p = rp[k];
                int rl = (int)(p >> 56);
                unsigned colb = (unsigned)(p >> 32) & 0xFFFFFFu;   // col<<7
                int pos = atomicAdd(&rcur[rl], 1);    // LDS atomic
                ebuf[pos] = ((p & 0xFFFFFFFFull) << 32) | (ull)colb;
            }
        }
        __syncthreads();
        for (int j = t; j < len; j += 512)
            edges[s + j] = ebuf[j];                   // coalesced
    } else {
        for (int j = s + t; j < e; j += 512) {
            ull p = etmp[j];
            int rl = (int)(p >> 56);
            unsigned colb = (unsigned)(p >> 32) & 0xFFFFFFu;
            int pos = atomicAdd(&rcur[rl], 1);
            edges[pos] = ((p & 0xFFFFFFFFull) << 32) | (ull)colb;
        }
    }
}

// ------------------------------------------------------------------- GEMM
// MFMA bf16: H[M,64] = X[M,K] @ W[64,K]^T + b, output bf16.
template <int K, typename XT>
__global__ __launch_bounds__(256) void gemm_mfma(const XT* __restrict__ X,
                                                 const float* __restrict__ W,
                                                 const float* __restrict__ B,
                                                 ushort* __restrict__ H) {
    constexpr int KS = K / 32;
    int wave = threadIdx.x >> 6;
    int lane = threadIdx.x & 63;
    int quad = lane >> 4;
    int l16  = lane & 15;
    int rowBase = blockIdx.x * 64 + wave * 16;
    int arow = rowBase + l16;
    if (arow > N_NODES - 1) arow = N_NODES - 1;   // clamp OOB loads (stores guarded)

    short8 a[KS];
#pragma unroll
    for (int ks = 0; ks < KS; ks++) {
        int k = ks * 32 + quad * 8;
        if constexpr (sizeof(XT) == 2) {
            a[ks] = *reinterpret_cast<const short8*>(X + (size_t)arow * K + k);
        } else {
            const float4* src = reinterpret_cast<const float4*>(X + (size_t)arow * K + k);
            float4 t0 = src[0], t1 = src[1];
            union { short8 v; ushort u[8]; } cv;
            cv.u[0] = rne_bf16(t0.x); cv.u[1] = rne_bf16(t0.y);
            cv.u[2] = rne_bf16(t0.z); cv.u[3] = rne_bf16(t0.w);
            cv.u[4] = rne_bf16(t1.x); cv.u[5] = rne_bf16(t1.y);
            cv.u[6] = rne_bf16(t1.z); cv.u[7] = rne_bf16(t1.w);
            a[ks] = cv.v;
        }
    }

    f32x4 acc[4];
#pragma unroll
    for (int nt = 0; nt < 4; nt++) acc[nt] = 0.f;

#pragma unroll
    for (int nt = 0; nt < 4; nt++) {
        int brow = nt * 16 + l16;                 // W row = output channel n
#pragma unroll
        for (int ks = 0; ks < KS; ks++) {
            int k = ks * 32 + quad * 8;
            const float4* src = reinterpret_cast<const float4*>(W + brow * K + k);
            float4 t0 = src[0], t1 = src[1];
            union { short8 v; ushort u[8]; } cv;
            cv.u[0] = rne_bf16(t0.x); cv.u[1] = rne_bf16(t0.y);
            cv.u[2] = rne_bf16(t0.z); cv.u[3] = rne_bf16(t0.w);
            cv.u[4] = rne_bf16(t1.x); cv.u[5] = rne_bf16(t1.y);
            cv.u[6] = rne_bf16(t1.z); cv.u[7] = rne_bf16(t1.w);
            acc[nt] = __builtin_amdgcn_mfma_f32_16x16x32_bf16(a[ks], cv.v, acc[nt], 0, 0, 0);
        }
    }

#pragma unroll
    for (int nt = 0; nt < 4; nt++) {
        int n = nt * 16 + l16;
        float bv = B[n];
#pragma unroll
        for (int reg = 0; reg < 4; reg++) {
            int m = rowBase + quad * 4 + reg;
            if (m < N_NODES) H[(size_t)m * HID + n] = rne_bf16(acc[nt][reg] + bv);
        }
    }
}

// ------------------------------------------------------------------- SpMM
// Row-per-wave, dwordx4 gathers (8 edges/instr, 16 random lines each),
// 4 groups issued then sched_barrier(0) pins consumption after issue
// (round-9 proven: 51.2us, VGPR 28, no scratch). bf16 unpack = shift/and+fma.
// POOL variant (layer 3): X3 consumed only by pool -> skip X3 write, read
// X1/X2 rows and atomicAdd (X1+X2+relu(acc)) into L2-resident sums.
template <bool POOL>
__global__ __launch_bounds__(256) void spmm_relu(const int* __restrict__ row_ptr,
                                                 const ull* __restrict__ edges,
                                                 const ushort* __restrict__ Hin,
                                                 ushort* __restrict__ Xout,
                                                 const ushort* __restrict__ X1p,
                                                 const ushort* __restrict__ X2p,
                                                 const int* __restrict__ batch,
                                                 float* __restrict__ sums) {
    int wid  = (blockIdx.x * 256 + threadIdx.x) >> 6;
    int lane = threadIdx.x & 63;
    if (wid >= N_NODES) return;
    int r = __builtin_amdgcn_readfirstlane(wid);  // wave-uniform -> s_loads
    int s   = row_ptr[r];
    int end = row_ptr[r + 1];
    int g8 = lane >> 3;                           // edge slot within group
    unsigned foff = (unsigned)(lane & 7) * 16u;   // feature-octet byte offset
    const char* Hb = (const char*)Hin;

    float acc[8];
#pragma unroll
    for (int j = 0; j < 8; j++) acc[j] = 0.f;

    for (int e = s; e < end; e += 32) {           // 4 groups of 8 edges
        int i0 = e + g8, i1 = e + 8 + g8, i2 = e + 16 + g8, i3 = e + 24 + g8;
        bool k0 = i0 < end, k1 = i1 < end, k2 = i2 < end, k3 = i3 < end;
        ull p0 = edges[k0 ? i0 : end - 1];
        ull p1 = edges[k1 ? i1 : end - 1];
        ull p2 = edges[k2 ? i2 : end - 1];
        ull p3 = edges[k3 ? i3 : end - 1];
        float v0 = k0 ? __uint_as_float((unsigned)(p0 >> 32)) : 0.f;
        float v1 = k1 ? __uint_as_float((unsigned)(p1 >> 32)) : 0.f;
        float v2 = k2 ? __uint_as_float((unsigned)(p2 >> 32)) : 0.f;
        float v3 = k3 ? __uint_as_float((unsigned)(p3 >> 32)) : 0.f;
        // issue all 4 gathers (lo32 of record = col<<7 byte offset)
        uint4 g0 = *reinterpret_cast<const uint4*>(Hb + ((unsigned)p0 + foff));
        uint4 g1 = *reinterpret_cast<const uint4*>(Hb + ((unsigned)p1 + foff));
        uint4 g2 = *reinterpret_cast<const uint4*>(Hb + ((unsigned)p2 + foff));
        uint4 g3 = *reinterpret_cast<const uint4*>(Hb + ((unsigned)p3 + foff));
        __builtin_amdgcn_sched_barrier(0);        // pin: no consume before issue
        acc[0] = fmaf(v0, __uint_as_float(g0.x << 16),         acc[0]);
        acc[1] = fmaf(v0, __uint_as_float(g0.x & 0xffff0000u), acc[1]);
        acc[2] = fmaf(v0, __uint_as_float(g0.y << 16),         acc[2]);
        acc[3] = fmaf(v0, __uint_as_float(g0.y & 0xffff0000u), acc[3]);
        acc[4] = fmaf(v0, __uint_as_float(g0.z << 16),         acc[4]);
        acc[5] = fmaf(v0, __uint_as_float(g0.z & 0xffff0000u), acc[5]);
        acc[6] = fmaf(v0, __uint_as_float(g0.w << 16),         acc[6]);
        acc[7] = fmaf(v0, __uint_as_float(g0.w & 0xffff0000u), acc[7]);
        acc[0] = fmaf(v1, __uint_as_float(g1.x << 16),         acc[0]);
        acc[1] = fmaf(v1, __uint_as_float(g1.x & 0xffff0000u), acc[1]);
        acc[2] = fmaf(v1, __uint_as_float(g1.y << 16),         acc[2]);
        acc[3] = fmaf(v1, __uint_as_float(g1.y & 0xffff0000u), acc[3]);
        acc[4] = fmaf(v1, __uint_as_float(g1.z << 16),         acc[4]);
        acc[5] = fmaf(v1, __uint_as_float(g1.z & 0xffff0000u), acc[5]);
        acc[6] = fmaf(v1, __uint_as_float(g1.w << 16),         acc[6]);
        acc[7] = fmaf(v1, __uint_as_float(g1.w & 0xffff0000u), acc[7]);
        acc[0] = fmaf(v2, __uint_as_float(g2.x << 16),         acc[0]);
        acc[1] = fmaf(v2, __uint_as_float(g2.x & 0xffff0000u), acc[1]);
        acc[2] = fmaf(v2, __uint_as_float(g2.y << 16),         acc[2]);
        acc[3] = fmaf(v2, __uint_as_float(g2.y & 0xffff0000u), acc[3]);
        acc[4] = fmaf(v2, __uint_as_float(g2.z << 16),         acc[4]);
        acc[5] = fmaf(v2, __uint_as_float(g2.z & 0xffff0000u), acc[5]);
        acc[6] = fmaf(v2, __uint_as_float(g2.w << 16),         acc[6]);
        acc[7] = fmaf(v2, __uint_as_float(g2.w & 0xffff0000u), acc[7]);
        acc[0] = fmaf(v3, __uint_as_float(g3.x << 16),         acc[0]);
        acc[1] = fmaf(v3, __uint_as_float(g3.x & 0xffff0000u), acc[1]);
        acc[2] = fmaf(v3, __uint_as_float(g3.y << 16),         acc[2]);
        acc[3] = fmaf(v3, __uint_as_float(g3.y & 0xffff0000u), acc[3]);
        acc[4] = fmaf(v3, __uint_as_float(g3.z << 16),         acc[4]);
        acc[5] = fmaf(v3, __uint_as_float(g3.z & 0xffff0000u), acc[5]);
        acc[6] = fmaf(v3, __uint_as_float(g3.w << 16),         acc[6]);
        acc[7] = fmaf(v3, __uint_as_float(g3.w & 0xffff0000u), acc[7]);
    }

    // fold the 8 edge-groups (lane bits 3..5)
#pragma unroll
    for (int m = 8; m < 64; m <<= 1) {
#pragma unroll
        for (int j = 0; j < 8; j++) acc[j] += __shfl_xor(acc[j], m, 64);
    }

    if (lane < 8) {
        if constexpr (!POOL) {
            union { short8 v; ushort u[8]; } o;
#pragma unroll
            for (int j = 0; j < 8; j++) o.u[j] = rne_bf16(fmaxf(acc[j], 0.f));
            *reinterpret_cast<short8*>(Xout + (size_t)r * HID + lane * 8) = o.v;
        } else {
            union { short8 v; ushort u[8]; } u1, u2;
            u1.v = *reinterpret_cast<const short8*>(X1p + (size_t)r * HID + lane * 8);
            u2.v = *reinterpret_cast<const short8*>(X2p + (size_t)r * HID + lane * 8);
            int g = batch[r];
            float* dst = sums + g * HID + lane * 8;
#pragma unroll
            for (int j = 0; j < 8; j++)
                atomicAdd(&dst[j], fmaxf(acc[j], 0.f) + bf2f(u1.u[j]) + bf2f(u2.u[j]));
        }
    }
}

// ------------------------------------------------------------------- Head
__global__ __launch_bounds__(64) void head_kernel(const float* __restrict__ sums,
                                                  const int* __restrict__ batch,
                                                  const float* __restrict__ Wout,
                                                  const float* __restrict__ bout,
                                                  float* __restrict__ out) {
    int g = blockIdx.x;
    int t = threadIdx.x;
    __shared__ float pr[HID];
    __shared__ float lg[OUT_DIM];
    __shared__ float mx, sm;
    auto lb = [&](int key) {
        int lo = 0, hi = N_NODES;
        while (lo < hi) {
            int mid = (lo + hi) >> 1;
            if (batch[mid] < key) lo = mid + 1; else hi = mid;
        }
        return lo;
    };
    int cnt = lb(g + 1) - lb(g);
    float denom = 3.0f * (float)(cnt > 1 ? cnt : 1);
    pr[t] = sums[g * HID + t] / denom;
    __syncthreads();
    if (t < OUT_DIM) {
        float a = bout[t];
        for (int k = 0; k < HID; k++) a += pr[k] * Wout[t * HID + k];
        lg[t] = a;
    }
    __syncthreads();
    if (t == 0) {
        float m = lg[0];
        for (int j = 1; j < OUT_DIM; j++) m = fmaxf(m, lg[j]);
        float s = 0.f;
        for (int j = 0; j < OUT_DIM; j++) s += expf(lg[j] - m);
        mx = m; sm = s;
    }
    __syncthreads();
    if (t < OUT_DIM) out[g * OUT_DIM + t] = expf(lg[t] - mx) / sm;
}

// ---------------------------------------------------------------- launcher
extern "C" void kernel_launch(void* const* d_in, const int* in_sizes, int n_in,
                              void* d_out, int out_size, void* d_ws, size_t ws_size,
                              hipStream_t stream) {
    const float* X    = (const float*)d_in[0];
    const float* vals = (const float*)d_in[1];
    const float* W1   = (const float*)d_in[2];
    const float* b1   = (const float*)d_in[3];
    const float* W2   = (const float*)d_in[4];
    const float* b2   = (const float*)d_in[5];
    const float* W3   = (const float*)d_in[6];
    const float* b3   = (const float*)d_in[7];
    const float* Wout = (const float*)d_in[8];
    const float* bout = (const float*)d_in[9];
    const int*   rows = (const int*)d_in[10];
    const int*   cols = (const int*)d_in[11];
    const int*   batch= (const int*)d_in[12];
    float* out = (float*)d_out;

    char* p = (char*)d_ws;
    auto carve = [&](size_t bytes) {
        void* q = (void*)p;
        p += (bytes + 255) & ~(size_t)255;
        return q;
    };
    ushort* h     = (ushort*)carve((size_t)N_NODES * HID * 2);
    ushort* X1    = (ushort*)carve((size_t)N_NODES * HID * 4);  // oversized: aliases etmp
    ushort* X2    = (ushort*)carve((size_t)N_NODES * HID * 2);
    int*   histT  = (int*)  carve((size_t)NTILES * NBUCKET * 4);
    int*   gcur   = (int*)  carve((size_t)NBUCKET * CPAD * 4);
    int*   base   = (int*)  carve((size_t)(NBUCKET + 1) * 4);
    int*   row_ptr= (int*)  carve((size_t)(N_NODES + 1) * 4);
    float* sums   = (float*)carve(N_GRAPHS * HID * 4);
    ull*   edges  = (ull*)  carve((size_t)N_EDGES * 8);
    // etmp aliases X1: etmp dead (after bucket_sort) before spmm1 writes X1.
    ull*   etmp   = (ull*)X1;
    (void)ws_size; (void)in_sizes; (void)n_in; (void)out_size;

    // ---- build CSR: hist -> tiny scan (also zeroes sums) -> scatter -> sort
    hipMemsetAsync(gcur, 0, (size_t)NBUCKET * CPAD * 4, stream);
    hist391<<<NTILES, 1024, 0, stream>>>(rows, histT, gcur);
    scan392<<<1, 512, 0, stream>>>(gcur, base, sums);
    scatter_pass<<<NTILES, 1024, 0, stream>>>(rows, cols, vals, histT, gcur, etmp);
    bucket_sort<<<NBUCKET, 512, 0, stream>>>(base, etmp, edges, row_ptr);

    const int gemm_grid = (N_NODES + 63) / 64;   // 64 rows/block
    const int spmm_grid = (N_NODES + 3) / 4;     // 1 row/wave, 4 waves/block

    // ---- layers (bf16 activations; layer-3 spmm fuses the pool)
    gemm_mfma<IN_DIM, float><<<gemm_grid, 256, 0, stream>>>(X, W1, b1, h);
    spmm_relu<false><<<spmm_grid, 256, 0, stream>>>(row_ptr, edges, h, X1,
                                                    nullptr, nullptr, nullptr, nullptr);
    gemm_mfma<HID, ushort><<<gemm_grid, 256, 0, stream>>>(X1, W2, b2, h);
    spmm_relu<false><<<spmm_grid, 256, 0, stream>>>(row_ptr, edges, h, X2,
                                                    nullptr, nullptr, nullptr, nullptr);
    gemm_mfma<HID, ushort><<<gemm_grid, 256, 0, stream>>>(X2, W3, b3, h);
    spmm_relu<true><<<spmm_grid, 256, 0, stream>>>(row_ptr, edges, h, nullptr,
                                                   X1, X2, batch, sums);

    // ---- head (pool was fused into spmm3)
    head_kernel<<<N_GRAPHS, 64, 0, stream>>>(sums, batch, Wout, bout, out);
}

// Round 13
// 441.224 us; speedup vs baseline: 3.5741x; 3.5741x over previous
//
#include <hip/hip_runtime.h>
#include <hip/hip_bf16.h>
#include <math.h>

#define N_NODES   100000
#define N_EDGES   3200000
#define IN_DIM    128
#define HID       64
#define OUT_DIM   10
#define N_GRAPHS  64

// Radix geometry: bucket = row >> 8 (256 rows/bucket), NBUCKET=391.
// Tile = 6250 edges, NTILES=512 = 2 blocks/CU. LDS-staged coalesced writes
// everywhere (round-1 lesson: random 8B global stores = 8x write amp).
// Round-11/12 lesson: fusing pool into spmm3 fired 6.4M device-scope
// atomics into 256 cache lines -> serialized at the cross-XCD coherence
// point (1300us, 200MB writes). Pool MUST pre-reduce 32 rows/wave in
// registers (200k atomics) -> separate pool_fused kernel, as here.
#define BUCKET_SHIFT 8
#define BUCKET_ROWS  256
#define NBUCKET ((N_NODES + BUCKET_ROWS - 1) >> BUCKET_SHIFT)     // 391
#define TILE_EDGES 6250                                           // 512*6250 = 3.2M exact
#define NTILES (N_EDGES / TILE_EDGES)                             // 512
#define CPAD 16       // cursor padding: 16 ints = 64B line per bucket
#define CAP  9216     // bucket mean 8192, sigma ~90 -> 11-sigma margin
#define KMAX 18       // CAP / 512

typedef unsigned long long ull;
typedef unsigned short ushort;
typedef __attribute__((ext_vector_type(8))) short short8;   // 8 bf16 (4 VGPRs)
typedef __attribute__((ext_vector_type(4))) float f32x4;    // MFMA C/D

__device__ __forceinline__ ushort rne_bf16(float x) {
    unsigned u = __float_as_uint(x);
    return (ushort)((u + 0x7fffu + ((u >> 16) & 1u)) >> 16);
}
__device__ __forceinline__ float bf2f(ushort u) {
    return __uint_as_float((unsigned)u << 16);
}

// ---------------------------------------------------------------- hist
__global__ __launch_bounds__(1024) void hist391(const int* __restrict__ rows,
                                                int* __restrict__ histT,
                                                int* __restrict__ gcur) {
    __shared__ int h[NBUCKET];
    int t = threadIdx.x, tile = blockIdx.x;
    for (int i = t; i < NBUCKET; i += 1024) h[i] = 0;
    __syncthreads();
    int base = tile * TILE_EDGES;
#pragma unroll
    for (int k = 0; k < 7; k++) {
        int idx = k * 1024 + t;
        if (idx < TILE_EDGES) atomicAdd(&h[rows[base + idx] >> BUCKET_SHIFT], 1);
    }
    __syncthreads();
    for (int i = t; i < NBUCKET; i += 1024) {
        int v = h[i];
        histT[tile * NBUCKET + i] = v;
        if (v) atomicAdd(&gcur[i * CPAD], v);
    }
}

// ---------------------------------------------------------------- scan
// Exclusive-scan 391 bucket totals -> base[]; reset padded cursors; zero sums.
__global__ __launch_bounds__(512) void scan392(int* __restrict__ gcur,
                                               int* __restrict__ base,
                                               float* __restrict__ sums) {
    __shared__ int sc[512];
    int t = threadIdx.x;
    for (int i = t; i < N_GRAPHS * HID; i += 512) sums[i] = 0.f;
    int cntv = (t < NBUCKET) ? gcur[t * CPAD] : 0;
    sc[t] = cntv;
    __syncthreads();
    for (int off = 1; off < 512; off <<= 1) {
        int x = (t >= off) ? sc[t - off] : 0;
        __syncthreads();
        sc[t] += x;
        __syncthreads();
    }
    int excl = sc[t] - cntv;
    if (t < NBUCKET) { base[t] = excl; gcur[t * CPAD] = excl; }
    if (t == NBUCKET) base[NBUCKET] = excl;   // == N_EDGES
}

// ---------------------------------------------------------------- scatter
// Record: rowLocal(8b) | colbyte(24b, = col<<7) || val_f32(32b).
__global__ __launch_bounds__(1024) void scatter_pass(const int* __restrict__ rows,
                                                     const int* __restrict__ cols,
                                                     const float* __restrict__ vals,
                                                     const int* __restrict__ histT,
                                                     int* __restrict__ gcur,
                                                     ull* __restrict__ etmp) {
    __shared__ ull ebuf[TILE_EDGES];       // 50,000 B
    __shared__ ushort bkt[TILE_EDGES];     // 12,500 B
    __shared__ int sc[512];
    __shared__ int lcur[NBUCKET];
    __shared__ int gdelta[NBUCKET];        // total ~67.7 KB -> 2 blk/CU
    int t = threadIdx.x, tile = blockIdx.x;

    int cntv = 0;
    if (t < 512) {
        cntv = (t < NBUCKET) ? histT[tile * NBUCKET + t] : 0;
        sc[t] = cntv;
    }
    __syncthreads();
    for (int off = 1; off < 512; off <<= 1) {
        int x = 0;
        if (t < 512 && t >= off) x = sc[t - off];
        __syncthreads();
        if (t < 512) sc[t] += x;
        __syncthreads();
    }
    if (t < NBUCKET) {
        int excl = sc[t] - cntv;
        lcur[t] = excl;
        int gbase = cntv ? atomicAdd(&gcur[t * CPAD], cntv) : 0;
        gdelta[t] = gbase - excl;
    }
    __syncthreads();

    int base = tile * TILE_EDGES;
#pragma unroll
    for (int k = 0; k < 7; k++) {
        int idx = k * 1024 + t;
        if (idx < TILE_EDGES) {
            int e = base + idx;
            int r = rows[e];
            int b = r >> BUCKET_SHIFT;
            int pos = atomicAdd(&lcur[b], 1);     // LDS atomic, block-local
            unsigned hi = ((unsigned)(r & (BUCKET_ROWS - 1)) << 24)
                        | ((unsigned)cols[e] << 7);
            ebuf[pos] = ((ull)hi << 32) | (ull)__float_as_uint(vals[e]);
            bkt[pos] = (ushort)b;
        }
    }
    __syncthreads();
    for (int j = t; j < TILE_EDGES; j += 1024)
        etmp[gdelta[bkt[j]] + j] = ebuf[j];       // coalesced within runs
}

// ---------------------------------------------------------------- pass C
__global__ __launch_bounds__(512) void bucket_sort(const int* __restrict__ base,
                                                   const ull* __restrict__ etmp,
                                                   ull* __restrict__ edges,
                                                   int* __restrict__ row_ptr) {
    __shared__ int rcnt[BUCKET_ROWS];
    __shared__ int roff[BUCKET_ROWS];
    __shared__ int rcur[BUCKET_ROWS];
    __shared__ ull ebuf[CAP];              // 73,728 B -> 2 blk/CU
    int b = blockIdx.x, t = threadIdx.x;
    int s = base[b];
    int e = base[b + 1];
    int len = e - s;
    bool staged = (len <= CAP);

    ull rp[KMAX];
    if (t < BUCKET_ROWS) rcnt[t] = 0;
    __syncthreads();
    if (staged) {
#pragma unroll
        for (int k = 0; k < KMAX; k++) {
            int j = s + t + k * 512;
            if (j < e) { rp[k] = etmp[j]; atomicAdd(&rcnt[(int)(rp[k] >> 56)], 1); }
        }
    } else {
        for (int j = s + t; j < e; j += 512)
            atomicAdd(&rcnt[(int)(etmp[j] >> 56)], 1);
    }
    __syncthreads();
    if (t < BUCKET_ROWS) roff[t] = rcnt[t];
    __syncthreads();
    for (int off = 1; off < BUCKET_ROWS; off <<= 1) {
        int x = (t >= off && t < BUCKET_ROWS) ? roff[t - off] : 0;
        __syncthreads();
        if (t < BUCKET_ROWS) roff[t] += x;
        __syncthreads();
    }
    if (t < BUCKET_ROWS) {
        int excl = roff[t] - rcnt[t];
        rcur[t] = staged ? excl : s + excl;
        int grow = b * BUCKET_ROWS + t;
        if (grow < N_NODES) row_ptr[grow] = s + excl;
    }
    if (b == NBUCKET - 1 && t == 0) row_ptr[N_NODES] = N_EDGES;
    __syncthreads();

    if (staged) {
#pragma unroll
        for (int k = 0; k < KMAX; k++) {
            int j = s + t + k * 512;
            if (j < e) {
                ull p = rp[k];
                int rl = (int)(p >> 56);
                unsigned colb = (unsigned)(p >> 32) & 0xFFFFFFu;   // col<<7
                int pos = atomicAdd(&rcur[rl], 1);    // LDS atomic
                ebuf[pos] = ((p & 0xFFFFFFFFull) << 32) | (ull)colb;
            }
        }
        __syncthreads();
        for (int j = t; j < len; j += 512)
            edges[s + j] = ebuf[j];                   // coalesced
    } else {
        for (int j = s + t; j < e; j += 512) {
            ull p = etmp[j];
            int rl = (int)(p >> 56);
            unsigned colb = (unsigned)(p >> 32) & 0xFFFFFFu;
            int pos = atomicAdd(&rcur[rl], 1);
            edges[pos] = ((p & 0xFFFFFFFFull) << 32) | (ull)colb;
        }
    }
}

// ------------------------------------------------------------------- GEMM
template <int K, typename XT>
__global__ __launch_bounds__(256) void gemm_mfma(const XT* __restrict__ X,
                                                 const float* __restrict__ W,
                                                 const float* __restrict__ B,
                                                 ushort* __restrict__ H) {
    constexpr int KS = K / 32;
    int wave = threadIdx.x >> 6;
    int lane = threadIdx.x & 63;
    int quad = lane >> 4;
    int l16  = lane & 15;
    int rowBase = blockIdx.x * 64 + wave * 16;
    int arow = rowBase + l16;
    if (arow > N_NODES - 1) arow = N_NODES - 1;   // clamp OOB loads (stores guarded)

    short8 a[KS];
#pragma unroll
    for (int ks = 0; ks < KS; ks++) {
        int k = ks * 32 + quad * 8;
        if constexpr (sizeof(XT) == 2) {
            a[ks] = *reinterpret_cast<const short8*>(X + (size_t)arow * K + k);
        } else {
            const float4* src = reinterpret_cast<const float4*>(X + (size_t)arow * K + k);
            float4 t0 = src[0], t1 = src[1];
            union { short8 v; ushort u[8]; } cv;
            cv.u[0] = rne_bf16(t0.x); cv.u[1] = rne_bf16(t0.y);
            cv.u[2] = rne_bf16(t0.z); cv.u[3] = rne_bf16(t0.w);
            cv.u[4] = rne_bf16(t1.x); cv.u[5] = rne_bf16(t1.y);
            cv.u[6] = rne_bf16(t1.z); cv.u[7] = rne_bf16(t1.w);
            a[ks] = cv.v;
        }
    }

    f32x4 acc[4];
#pragma unroll
    for (int nt = 0; nt < 4; nt++) acc[nt] = 0.f;

#pragma unroll
    for (int nt = 0; nt < 4; nt++) {
        int brow = nt * 16 + l16;                 // W row = output channel n
#pragma unroll
        for (int ks = 0; ks < KS; ks++) {
            int k = ks * 32 + quad * 8;
            const float4* src = reinterpret_cast<const float4*>(W + brow * K + k);
            float4 t0 = src[0], t1 = src[1];
            union { short8 v; ushort u[8]; } cv;
            cv.u[0] = rne_bf16(t0.x); cv.u[1] = rne_bf16(t0.y);
            cv.u[2] = rne_bf16(t0.z); cv.u[3] = rne_bf16(t0.w);
            cv.u[4] = rne_bf16(t1.x); cv.u[5] = rne_bf16(t1.y);
            cv.u[6] = rne_bf16(t1.z); cv.u[7] = rne_bf16(t1.w);
            acc[nt] = __builtin_amdgcn_mfma_f32_16x16x32_bf16(a[ks], cv.v, acc[nt], 0, 0, 0);
        }
    }

#pragma unroll
    for (int nt = 0; nt < 4; nt++) {
        int n = nt * 16 + l16;
        float bv = B[n];
#pragma unroll
        for (int reg = 0; reg < 4; reg++) {
            int m = rowBase + quad * 4 + reg;
            if (m < N_NODES) H[(size_t)m * HID + n] = rne_bf16(acc[nt][reg] + bv);
        }
    }
}

// ------------------------------------------------------------------- SpMM
// Row-per-wave, dwordx4 gathers (8 edges/instr, 16 random lines each),
// 4 groups issued then sched_barrier(0) pins consumption after issue
// (round-9 proven: 51.2us, VGPR 28, no scratch).
__global__ __launch_bounds__(256) void spmm_relu(const int* __restrict__ row_ptr,
                                                 const ull* __restrict__ edges,
                                                 const ushort* __restrict__ Hin,
                                                 ushort* __restrict__ Xout) {
    int wid  = (blockIdx.x * 256 + threadIdx.x) >> 6;
    int lane = threadIdx.x & 63;
    if (wid >= N_NODES) return;
    int r = __builtin_amdgcn_readfirstlane(wid);  // wave-uniform -> s_loads
    int s   = row_ptr[r];
    int end = row_ptr[r + 1];
    int g8 = lane >> 3;                           // edge slot within group
    unsigned foff = (unsigned)(lane & 7) * 16u;   // feature-octet byte offset
    const char* Hb = (const char*)Hin;

    float acc[8];
#pragma unroll
    for (int j = 0; j < 8; j++) acc[j] = 0.f;

    for (int e = s; e < end; e += 32) {           // 4 groups of 8 edges
        int i0 = e + g8, i1 = e + 8 + g8, i2 = e + 16 + g8, i3 = e + 24 + g8;
        bool k0 = i0 < end, k1 = i1 < end, k2 = i2 < end, k3 = i3 < end;
        ull p0 = edges[k0 ? i0 : end - 1];        // end>=1 when loop entered
        ull p1 = edges[k1 ? i1 : end - 1];
        ull p2 = edges[k2 ? i2 : end - 1];
        ull p3 = edges[k3 ? i3 : end - 1];
        float v0 = k0 ? __uint_as_float((unsigned)(p0 >> 32)) : 0.f;
        float v1 = k1 ? __uint_as_float((unsigned)(p1 >> 32)) : 0.f;
        float v2 = k2 ? __uint_as_float((unsigned)(p2 >> 32)) : 0.f;
        float v3 = k3 ? __uint_as_float((unsigned)(p3 >> 32)) : 0.f;
        // issue all 4 gathers (lo32 of record = col<<7 byte offset)
        uint4 g0 = *reinterpret_cast<const uint4*>(Hb + ((unsigned)p0 + foff));
        uint4 g1 = *reinterpret_cast<const uint4*>(Hb + ((unsigned)p1 + foff));
        uint4 g2 = *reinterpret_cast<const uint4*>(Hb + ((unsigned)p2 + foff));
        uint4 g3 = *reinterpret_cast<const uint4*>(Hb + ((unsigned)p3 + foff));
        __builtin_amdgcn_sched_barrier(0);        // pin: no consume before all issued
        acc[0] = fmaf(v0, __uint_as_float(g0.x << 16),         acc[0]);
        acc[1] = fmaf(v0, __uint_as_float(g0.x & 0xffff0000u), acc[1]);
        acc[2] = fmaf(v0, __uint_as_float(g0.y << 16),         acc[2]);
        acc[3] = fmaf(v0, __uint_as_float(g0.y & 0xffff0000u), acc[3]);
        acc[4] = fmaf(v0, __uint_as_float(g0.z << 16),         acc[4]);
        acc[5] = fmaf(v0, __uint_as_float(g0.z & 0xffff0000u), acc[5]);
        acc[6] = fmaf(v0, __uint_as_float(g0.w << 16),         acc[6]);
        acc[7] = fmaf(v0, __uint_as_float(g0.w & 0xffff0000u), acc[7]);
        acc[0] = fmaf(v1, __uint_as_float(g1.x << 16),         acc[0]);
        acc[1] = fmaf(v1, __uint_as_float(g1.x & 0xffff0000u), acc[1]);
        acc[2] = fmaf(v1, __uint_as_float(g1.y << 16),         acc[2]);
        acc[3] = fmaf(v1, __uint_as_float(g1.y & 0xffff0000u), acc[3]);
        acc[4] = fmaf(v1, __uint_as_float(g1.z << 16),         acc[4]);
        acc[5] = fmaf(v1, __uint_as_float(g1.z & 0xffff0000u), acc[5]);
        acc[6] = fmaf(v1, __uint_as_float(g1.w << 16),         acc[6]);
        acc[7] = fmaf(v1, __uint_as_float(g1.w & 0xffff0000u), acc[7]);
        acc[0] = fmaf(v2, __uint_as_float(g2.x << 16),         acc[0]);
        acc[1] = fmaf(v2, __uint_as_float(g2.x & 0xffff0000u), acc[1]);
        acc[2] = fmaf(v2, __uint_as_float(g2.y << 16),         acc[2]);
        acc[3] = fmaf(v2, __uint_as_float(g2.y & 0xffff0000u), acc[3]);
        acc[4] = fmaf(v2, __uint_as_float(g2.z << 16),         acc[4]);
        acc[5] = fmaf(v2, __uint_as_float(g2.z & 0xffff0000u), acc[5]);
        acc[6] = fmaf(v2, __uint_as_float(g2.w << 16),         acc[6]);
        acc[7] = fmaf(v2, __uint_as_float(g2.w & 0xffff0000u), acc[7]);
        acc[0] = fmaf(v3, __uint_as_float(g3.x << 16),         acc[0]);
        acc[1] = fmaf(v3, __uint_as_float(g3.x & 0xffff0000u), acc[1]);
        acc[2] = fmaf(v3, __uint_as_float(g3.y << 16),         acc[2]);
        acc[3] = fmaf(v3, __uint_as_float(g3.y & 0xffff0000u), acc[3]);
        acc[4] = fmaf(v3, __uint_as_float(g3.z << 16),         acc[4]);
        acc[5] = fmaf(v3, __uint_as_float(g3.z & 0xffff0000u), acc[5]);
        acc[6] = fmaf(v3, __uint_as_float(g3.w << 16),         acc[6]);
        acc[7] = fmaf(v3, __uint_as_float(g3.w & 0xffff0000u), acc[7]);
    }

    // fold the 8 edge-groups (lane bits 3..5)
#pragma unroll
    for (int m = 8; m < 64; m <<= 1) {
#pragma unroll
        for (int j = 0; j < 8; j++) acc[j] += __shfl_xor(acc[j], m, 64);
    }

    if (lane < 8) {
        union { short8 v; ushort u[8]; } o;
#pragma unroll
        for (int j = 0; j < 8; j++) o.u[j] = rne_bf16(fmaxf(acc[j], 0.f));
        *reinterpret_cast<short8*>(Xout + (size_t)r * HID + lane * 8) = o.v;
    }
}

// ------------------------------------------------------------------- Pool
// 32 rows per wave accumulated in registers -> ~1 atomic per segment per
// wave (~200k atomics total). Do NOT fuse into spmm (round-11/12 lesson:
// per-row atomics = 6.4M device-scope ops serialized at the coherence
// point = 1.3ms).
__global__ __launch_bounds__(256) void pool_fused(const ushort* __restrict__ X1,
                                                  const ushort* __restrict__ X2,
                                                  const ushort* __restrict__ X3,
                                                  const int* __restrict__ batch,
                                                  float* __restrict__ sums) {
    int lane = threadIdx.x & 63;
    int w = threadIdx.x >> 6;
    int n0 = blockIdx.x * 128 + w * 32;
    if (n0 >= N_NODES) return;
    int n1 = n0 + 32;
    if (n1 > N_NODES) n1 = N_NODES;
    int g_cur = __builtin_amdgcn_readfirstlane(batch[n0]);
    float acc = 0.f;
    for (int n = n0; n < n1; n++) {
        int g = __builtin_amdgcn_readfirstlane(batch[n]);
        if (g != g_cur) {
            atomicAdd(&sums[g_cur * HID + lane], acc);
            acc = 0.f; g_cur = g;
        }
        size_t base = (size_t)n * HID + lane;
        acc += bf2f(X1[base]) + bf2f(X2[base]) + bf2f(X3[base]);
    }
    atomicAdd(&sums[g_cur * HID + lane], acc);
}

// ------------------------------------------------------------------- Head
__global__ __launch_bounds__(64) void head_kernel(const float* __restrict__ sums,
                                                  const int* __restrict__ batch,
                                                  const float* __restrict__ Wout,
                                                  const float* __restrict__ bout,
                                                  float* __restrict__ out) {
    int g = blockIdx.x;
    int t = threadIdx.x;
    __shared__ float pr[HID];
    __shared__ float lg[OUT_DIM];
    __shared__ float mx, sm;
    auto lb = [&](int key) {
        int lo = 0, hi = N_NODES;
        while (lo < hi) {
            int mid = (lo + hi) >> 1;
            if (batch[mid] < key) lo = mid + 1; else hi = mid;
        }
        return lo;
    };
    int cnt = lb(g + 1) - lb(g);
    float denom = 3.0f * (float)(cnt > 1 ? cnt : 1);
    pr[t] = sums[g * HID + t] / denom;
    __syncthreads();
    if (t < OUT_DIM) {
        float a = bout[t];
        for (int k = 0; k < HID; k++) a += pr[k] * Wout[t * HID + k];
        lg[t] = a;
    }
    __syncthreads();
    if (t == 0) {
        float m = lg[0];
        for (int j = 1; j < OUT_DIM; j++) m = fmaxf(m, lg[j]);
        float s = 0.f;
        for (int j = 0; j < OUT_DIM; j++) s += expf(lg[j] - m);
        mx = m; sm = s;
    }
    __syncthreads();
    if (t < OUT_DIM) out[g * OUT_DIM + t] = expf(lg[t] - mx) / sm;
}

// ---------------------------------------------------------------- launcher
extern "C" void kernel_launch(void* const* d_in, const int* in_sizes, int n_in,
                              void* d_out, int out_size, void* d_ws, size_t ws_size,
                              hipStream_t stream) {
    const float* X    = (const float*)d_in[0];
    const float* vals = (const float*)d_in[1];
    const float* W1   = (const float*)d_in[2];
    const float* b1   = (const float*)d_in[3];
    const float* W2   = (const float*)d_in[4];
    const float* b2   = (const float*)d_in[5];
    const float* W3   = (const float*)d_in[6];
    const float* b3   = (const float*)d_in[7];
    const float* Wout = (const float*)d_in[8];
    const float* bout = (const float*)d_in[9];
    const int*   rows = (const int*)d_in[10];
    const int*   cols = (const int*)d_in[11];
    const int*   batch= (const int*)d_in[12];
    float* out = (float*)d_out;

    char* p = (char*)d_ws;
    auto carve = [&](size_t bytes) {
        void* q = (void*)p;
        p += (bytes + 255) & ~(size_t)255;
        return q;
    };
    ushort* h     = (ushort*)carve((size_t)N_NODES * HID * 2);
    ushort* X1    = (ushort*)carve((size_t)N_NODES * HID * 4);  // oversized: aliases etmp
    ushort* X2    = (ushort*)carve((size_t)N_NODES * HID * 2);
    ushort* X3    = (ushort*)carve((size_t)N_NODES * HID * 2);
    int*   histT  = (int*)  carve((size_t)NTILES * NBUCKET * 4);
    int*   gcur   = (int*)  carve((size_t)NBUCKET * CPAD * 4);
    int*   base   = (int*)  carve((size_t)(NBUCKET + 1) * 4);
    int*   row_ptr= (int*)  carve((size_t)(N_NODES + 1) * 4);
    float* sums   = (float*)carve(N_GRAPHS * HID * 4);
    ull*   edges  = (ull*)  carve((size_t)N_EDGES * 8);
    // etmp aliases X1: etmp dead (after bucket_sort) before spmm1 writes X1.
    ull*   etmp   = (ull*)X1;
    (void)ws_size; (void)in_sizes; (void)n_in; (void)out_size;

    // ---- build CSR: hist -> tiny scan (also zeroes sums) -> scatter -> sort
    hipMemsetAsync(gcur, 0, (size_t)NBUCKET * CPAD * 4, stream);
    hist391<<<NTILES, 1024, 0, stream>>>(rows, histT, gcur);
    scan392<<<1, 512, 0, stream>>>(gcur, base, sums);
    scatter_pass<<<NTILES, 1024, 0, stream>>>(rows, cols, vals, histT, gcur, etmp);
    bucket_sort<<<NBUCKET, 512, 0, stream>>>(base, etmp, edges, row_ptr);

    const int gemm_grid = (N_NODES + 63) / 64;   // 64 rows/block
    const int spmm_grid = (N_NODES + 3) / 4;     // 1 row/wave, 4 waves/block

    // ---- layers (X_l kept separately; pooling sums them later)
    gemm_mfma<IN_DIM, float><<<gemm_grid, 256, 0, stream>>>(X, W1, b1, h);
    spmm_relu<<<spmm_grid, 256, 0, stream>>>(row_ptr, edges, h, X1);
    gemm_mfma<HID, ushort><<<gemm_grid, 256, 0, stream>>>(X1, W2, b2, h);
    spmm_relu<<<spmm_grid, 256, 0, stream>>>(row_ptr, edges, h, X2);
    gemm_mfma<HID, ushort><<<gemm_grid, 256, 0, stream>>>(X2, W3, b3, h);
    spmm_relu<<<spmm_grid, 256, 0, stream>>>(row_ptr, edges, h, X3);

    // ---- pool + head
    pool_fused<<<(N_NODES + 127) / 128, 256, 0, stream>>>(X1, X2, X3, batch, sums);
    head_kernel<<<N_GRAPHS, 64, 0, stream>>>(sums, batch, Wout, bout, out);
}